// Round 9
// baseline (8545.560 us; speedup 1.0000x reference)
//
#include <hip/hip_runtime.h>
#include <math.h>

#define BB 64
#define SS 1024
#define CC 512
#define VV 140
#define AA 512
#define HH 512
#define TT 128
#define G4 2048   // 4*H
#define VA 652    // V+A
#define NCH 8     // flash S-chunks per batch

// clang-native vector for nontemporal builtins (HIP float4 is a class type)
typedef __attribute__((ext_vector_type(4))) float f4raw;
__device__ __forceinline__ float4 ntload4(const float4* p) {
    f4raw v = __builtin_nontemporal_load((const f4raw*)p);
    return make_float4(v.x, v.y, v.z, v.w);
}

// ---------------------------------------------------------------------------
// One-time precompute kernels
// ---------------------------------------------------------------------------

// p0[c] = sum_a Hcb[a]*Ic[a][c]; v0[k] = sum_a Hc[a][k]*Icb[a]; s0 = Hcb.Icb
__global__ void k_small(const float* __restrict__ Hc, const float* __restrict__ Hcb,
                        const float* __restrict__ Ic, const float* __restrict__ Icb,
                        float* __restrict__ p0, float* __restrict__ v0,
                        float* __restrict__ s0) {
    int t = threadIdx.x;  // 512
    float av = 0.f, pv = 0.f;
    for (int a = 0; a < AA; a++) {
        av += Hc[a * HH + t] * Icb[a];
        pv += Hcb[a] * Ic[a * CC + t];
    }
    v0[t] = av;
    p0[t] = pv;
    if (t == 0) {
        float s = 0.f;
        for (int a = 0; a < AA; a++) s += Hcb[a] * Icb[a];
        s0[0] = s;
    }
}

// P[k][c] = sum_a Hc[a][k] * Ic[a][c]     (P = Hc^T Ic, [512][512])
__global__ __launch_bounds__(256) void k_P(const float* __restrict__ Hc,
                                           const float* __restrict__ Ic,
                                           float* __restrict__ P) {
    int k = blockIdx.y;
    int c = blockIdx.x * 256 + threadIdx.x;
    float acc = 0.f;
    for (int a = 0; a < AA; a++) acc += Hc[a * HH + k] * Ic[a * CC + c];
    P[k * CC + c] = acc;
}

// Gtmp[g][c] = sum_a Wih[g][140+a] * Ic[a][c]   ([2048][512])
__global__ __launch_bounds__(256) void k_G(const float* __restrict__ Wih,
                                           const float* __restrict__ Ic,
                                           float* __restrict__ Gtmp) {
    int gb = blockIdx.y * 8;
    int c = blockIdx.x * 256 + threadIdx.x;
    float acc[8];
#pragma unroll
    for (int j = 0; j < 8; j++) acc[j] = 0.f;
    for (int a = 0; a < AA; a++) {
        float ic = Ic[a * CC + c];
#pragma unroll
        for (int j = 0; j < 8; j++) acc[j] += Wih[(size_t)(gb + j) * VA + VV + a] * ic;
    }
#pragma unroll
    for (int j = 0; j < 8; j++) Gtmp[(size_t)(gb + j) * CC + c] = acc[j];
}

// gate_bias[g] = b_ih[g] + b_hh[g] + sum_a Wih[g][140+a]*Icb[a]
__global__ void k_gate_bias(const float* __restrict__ Wih, const float* __restrict__ Icb,
                            const float* __restrict__ bih, const float* __restrict__ bhh,
                            float* __restrict__ gate_bias) {
    int g = blockIdx.x * 256 + threadIdx.x;
    float acc = bih[g] + bhh[g];
    for (int a = 0; a < AA; a++) acc += Wih[(size_t)g * VA + VV + a] * Icb[a];
    gate_bias[g] = acc;
}

// dst[c*R + r] = src[r*ld + col0 + c]  (tiled transpose)
__global__ void k_transpose(const float* __restrict__ src, float* __restrict__ dst,
                            int R, int Cc, int ld, int col0) {
    __shared__ float tile[32][33];
    int r0 = blockIdx.y * 32, c0 = blockIdx.x * 32;
    int tx = threadIdx.x, ty = threadIdx.y;  // 32 x 8
#pragma unroll
    for (int k = 0; k < 4; k++) {
        int r = r0 + ty + k * 8, c = c0 + tx;
        if (r < R && c < Cc) tile[ty + k * 8][tx] = src[(size_t)r * ld + col0 + c];
    }
    __syncthreads();
#pragma unroll
    for (int k = 0; k < 4; k++) {
        int c = c0 + ty + k * 8, r = r0 + tx;
        if (c < Cc && r < R) dst[(size_t)c * R + r] = tile[tx][ty + k * 8];
    }
}

// h=c=0, q' = p0, qb = s0, char = labels[:,0]
__global__ void k_init(const int* __restrict__ labels, const float* __restrict__ p0,
                       const float* __restrict__ s0, float* __restrict__ h,
                       float* __restrict__ cstA, float* __restrict__ qp,
                       float* __restrict__ qb, int* __restrict__ charrA) {
    int b = blockIdx.x, t = threadIdx.x;  // 64 x 512
    h[b * HH + t] = 0.f;
    cstA[b * HH + t] = 0.f;
    qp[b * CC + t] = p0[t];
    if (t == 0) {
        qb[b] = s0[0];
        charrA[b] = labels[b * TT];
    }
}

// ---------------------------------------------------------------------------
// Per-step kernels
// ---------------------------------------------------------------------------

#define ONLINE_UPDATE(score, xv)                                      \
    if ((score) > m) {                                                \
        float f_ = expf(m - (score));                                 \
        l = l * f_ + 1.f;                                             \
        _Pragma("unroll")                                             \
        for (int j = 0; j < 8; j++) acc[j] = acc[j] * f_ + (xv)[j];   \
        m = (score);                                                  \
    } else {                                                          \
        float p_ = expf((score) - m);                                 \
        l += p_;                                                      \
        _Pragma("unroll")                                             \
        for (int j = 0; j < 8; j++) acc[j] += p_ * (xv)[j];           \
    }

#define DOT8(xv) ((xv)[0] * qa.x + (xv)[1] * qa.y + (xv)[2] * qa.z + (xv)[3] * qa.w + \
                  (xv)[4] * qb4.x + (xv)[5] * qb4.y + (xv)[6] * qb4.z + (xv)[7] * qb4.w)

#define UNPACK8(xv, ra, rb) \
    (xv)[0] = ra.x; (xv)[1] = ra.y; (xv)[2] = ra.z; (xv)[3] = ra.w; \
    (xv)[4] = rb.x; (xv)[5] = rb.y; (xv)[6] = rb.z; (xv)[7] = rb.w;

// Flash attention pass over X. grid (NCH=8 chunks, 64 b), 512 threads (8 waves)
// = 512 blocks (2/CU). X loads are NON-TEMPORAL: X has zero reuse within a
// step and would otherwise evict GT/WhhT/P/Wout from L2 between kernels.
__global__ __launch_bounds__(512) void k_flash(const float* __restrict__ X,
                                               const float* __restrict__ qp,
                                               const float* __restrict__ qb,
                                               float* __restrict__ part_m,
                                               float* __restrict__ part_l,
                                               float* __restrict__ part_acc) {
    int b = blockIdx.y, chunk = blockIdx.x;
    int tid = threadIdx.x, w = tid >> 6, lane = tid & 63;
    const float inv_sqrt_a = 0.044194173824159216f;  // 1/sqrt(512)

    const float4* q4 = (const float4*)(qp + b * CC) + lane * 2;
    float4 qa = q4[0], qb4 = q4[1];
    float qoff = qb[b];

    float m = -INFINITY, l = 0.f;
    float acc[8];
#pragma unroll
    for (int j = 0; j < 8; j++) acc[j] = 0.f;

    int s0 = chunk * 128 + w * 16;
    const float* base = X + ((size_t)b * SS + s0) * CC;
    for (int i = 0; i < 16; i += 4) {
        const float4* xr0 = (const float4*)(base + (size_t)(i + 0) * CC) + lane * 2;
        const float4* xr1 = (const float4*)(base + (size_t)(i + 1) * CC) + lane * 2;
        const float4* xr2 = (const float4*)(base + (size_t)(i + 2) * CC) + lane * 2;
        const float4* xr3 = (const float4*)(base + (size_t)(i + 3) * CC) + lane * 2;
        float4 x0a = ntload4(xr0);
        float4 x0b = ntload4(xr0 + 1);
        float4 x1a = ntload4(xr1);
        float4 x1b = ntload4(xr1 + 1);
        float4 x2a = ntload4(xr2);
        float4 x2b = ntload4(xr2 + 1);
        float4 x3a = ntload4(xr3);
        float4 x3b = ntload4(xr3 + 1);
        float xv0[8], xv1[8], xv2[8], xv3[8];
        UNPACK8(xv0, x0a, x0b);
        UNPACK8(xv1, x1a, x1b);
        UNPACK8(xv2, x2a, x2b);
        UNPACK8(xv3, x3a, x3b);
        float d0 = DOT8(xv0);
        float d1 = DOT8(xv1);
        float d2 = DOT8(xv2);
        float d3 = DOT8(xv3);
#pragma unroll
        for (int off = 1; off < 64; off <<= 1) {
            d0 += __shfl_xor(d0, off, 64);
            d1 += __shfl_xor(d1, off, 64);
            d2 += __shfl_xor(d2, off, 64);
            d3 += __shfl_xor(d3, off, 64);
        }
        float sc0 = (d0 + qoff) * inv_sqrt_a;
        float sc1 = (d1 + qoff) * inv_sqrt_a;
        float sc2 = (d2 + qoff) * inv_sqrt_a;
        float sc3 = (d3 + qoff) * inv_sqrt_a;
        ONLINE_UPDATE(sc0, xv0);
        ONLINE_UPDATE(sc1, xv1);
        ONLINE_UPDATE(sc2, xv2);
        ONLINE_UPDATE(sc3, xv3);
    }

    // combine 8 waves -> one block partial
    __shared__ float lm[8], ll[8];
    __shared__ __align__(16) float lacc[8][512];
    if (lane == 0) lm[w] = m;
    __syncthreads();
    float M = lm[0];
#pragma unroll
    for (int j = 1; j < 8; j++) M = fmaxf(M, lm[j]);
    float f = expf(m - M);
    if (lane == 0) ll[w] = l * f;
#pragma unroll
    for (int j = 0; j < 8; j++) lacc[w][lane * 8 + j] = acc[j] * f;
    __syncthreads();
    float s = 0.f;
#pragma unroll
    for (int j = 0; j < 8; j++) s += lacc[j][tid];
    part_acc[((b * NCH + chunk) << 9) + tid] = s;
    if (tid == 0) {
        float lt = 0.f;
        for (int j = 0; j < 8; j++) lt += ll[j];
        part_m[b * NCH + chunk] = M;
        part_l[b * NCH + chunk] = lt;
    }
}

// Skinny GEMM: pg[cs][b][g] partial of  ywx.G^T (cs 0..3)  or  h.Whh^T (cs 4..7).
// grid (cs=8, gt=8, bt=4), 512 threads; thread = 2b x 4g tile.
// W is STREAMED directly from global in the FMA loop (no LDS wbuf, 1 barrier
// instead of 8): each wave's W row-slice read is 1 KB coalesced and identical
// across the 8 waves (L1 broadcast); the 4 bt-blocks share tiles via L2.
// i ascends 0..127 = old cchunk*32+i order -> per-output FMA chain unchanged.
__global__ __launch_bounds__(512) void k_gates(const float* __restrict__ part_m,
                                               const float* __restrict__ part_l,
                                               const float* __restrict__ part_acc,
                                               const float* __restrict__ h,
                                               const float* __restrict__ GT,
                                               const float* __restrict__ WhhT,
                                               float* __restrict__ pg) {
    int cs = blockIdx.x, gt = blockIdx.y, bt = blockIdx.z;
    int tid = threadIdx.x;
    int tg = tid & 63, tb = tid >> 6;  // tg: 64 col-groups of 4; tb: 8 b-pairs

    __shared__ __align__(16) float actT[128 * 16];  // [cc][bb]
    __shared__ float coefL[16][NCH];

    if (cs < 4) {
        if (tid < 16) {
            int b = bt * 16 + tid;
            float mv[NCH];
#pragma unroll
            for (int i = 0; i < NCH; i++) mv[i] = part_m[b * NCH + i];
            float M = mv[0];
#pragma unroll
            for (int i = 1; i < NCH; i++) M = fmaxf(M, mv[i]);
            float denom = 0.f;
            float ev[NCH];
#pragma unroll
            for (int i = 0; i < NCH; i++) {
                ev[i] = expf(mv[i] - M);
                denom += ev[i] * part_l[b * NCH + i];
            }
            float inv = 1.f / denom;
#pragma unroll
            for (int i = 0; i < NCH; i++) coefL[tid][i] = ev[i] * inv;
        }
        __syncthreads();
#pragma unroll
        for (int k = 0; k < 4; k++) {
            int idx = k * 512 + tid;
            int bb = idx >> 7, cc = idx & 127;
            int b = bt * 16 + bb;
            const float* pa = part_acc + (size_t)(b * NCH) * 512 + cs * 128 + cc;
            float v = 0.f;
#pragma unroll
            for (int i = 0; i < NCH; i++) v += coefL[bb][i] * pa[(size_t)i * 512];
            actT[cc * 16 + bb] = v;
        }
    } else {
#pragma unroll
        for (int k = 0; k < 4; k++) {
            int idx = k * 512 + tid;
            int bb = idx >> 7, cc = idx & 127;
            actT[cc * 16 + bb] = h[(bt * 16 + bb) * HH + (cs - 4) * 128 + cc];
        }
    }
    __syncthreads();

    const float* W = (cs < 4) ? (GT + (size_t)(cs * 128) * G4)
                              : (WhhT + (size_t)((cs - 4) * 128) * G4);
    const float* Wp = W + gt * 256 + tg * 4;
    float4 acc0 = make_float4(0, 0, 0, 0), acc1 = make_float4(0, 0, 0, 0);

#define FMA4(accv, sclr, wv)                    \
    accv.x += (sclr) * wv.x; accv.y += (sclr) * wv.y; \
    accv.z += (sclr) * wv.z; accv.w += (sclr) * wv.w;

#pragma unroll 8
    for (int i = 0; i < 128; i++) {
        float4 wv = *(const float4*)&Wp[(size_t)i * G4];
        float2 av = *(const float2*)&actT[i * 16 + tb * 2];
        FMA4(acc0, av.x, wv);
        FMA4(acc1, av.y, wv);
    }
#undef FMA4

    int b0 = bt * 16 + tb * 2;
    int g0 = gt * 256 + tg * 4;
    *(float4*)&pg[(size_t)(cs * BB + b0 + 0) * G4 + g0] = acc0;
    *(float4*)&pg[(size_t)(cs * BB + b0 + 1) * G4 + g0] = acc1;
}

// Fused update + qp. grid 256 blocks (b = bx>>2, quad = bx&3), 512 threads.
// All 4 quad-blocks of a batch redundantly compute gates+LSTM; quad 0 also
// does logits/argmax/out/qb and writes h/cst; every quad computes its
// 128-column quarter of next-step qp. cst/charr double-buffered (no races).
__global__ __launch_bounds__(512) void k_updqp(
    const float* __restrict__ pg, const float* __restrict__ gate_bias,
    const float* __restrict__ Wih0T, const float* __restrict__ Wout,
    const float* __restrict__ bout, const float* __restrict__ v0,
    const float* __restrict__ s0, const float* __restrict__ P,
    const float* __restrict__ p0,
    const float* __restrict__ cin, float* __restrict__ cout,
    const int* __restrict__ chin, int* __restrict__ chout,
    float* __restrict__ h, float* __restrict__ qp, float* __restrict__ qb,
    float* __restrict__ out, int t) {
    int bx = blockIdx.x, tid = threadIdx.x;
    int cb = bx >> 2, quad = bx & 3;
    int w = tid >> 6, lane = tid & 63;

    __shared__ __align__(16) float gl[G4];
    __shared__ __align__(16) float hl[HH];
    __shared__ float logl[VV];
    __shared__ float red[512];

    int ch = chin[cb];

    // 1. gates: g0 = tid*4; order: bias + Wih0T[ch] + pg j=0..7
    {
        int g0 = tid * 4;
        float4 a = *(const float4*)&gate_bias[g0];
        float4 wv = *(const float4*)&Wih0T[(size_t)ch * G4 + g0];
        a.x += wv.x; a.y += wv.y; a.z += wv.z; a.w += wv.w;
#pragma unroll
        for (int j = 0; j < 8; j++) {
            float4 p = *(const float4*)&pg[(size_t)(j * BB + cb) * G4 + g0];
            a.x += p.x; a.y += p.y; a.z += p.z; a.w += p.w;
        }
        *(float4*)&gl[g0] = a;
    }
    __syncthreads();

    // 2. LSTM cell (c-state ping-pong: read cin, write cout)
    {
        float ig = 1.f / (1.f + expf(-gl[tid]));
        float fg = 1.f / (1.f + expf(-gl[512 + tid]));
        float gg = tanhf(gl[1024 + tid]);
        float og = 1.f / (1.f + expf(-gl[1536 + tid]));
        float cn = fg * cin[cb * HH + tid] + ig * gg;
        float hn = og * tanhf(cn);
        if (quad == 0) {
            cout[cb * HH + tid] = cn;
            h[cb * HH + tid] = hn;
        }
        hl[tid] = hn;
    }
    __syncthreads();

    // 3+4. logits / argmax / out / qb: quad 0 only (block-uniform branch)
    if (quad == 0) {
        const float4* hr = (const float4*)hl + lane * 2;
        float4 h0 = hr[0], h1 = hr[1];
        for (int v = w; v < VV; v += 8) {
            const float4* wr = (const float4*)(Wout + (size_t)v * HH) + lane * 2;
            float4 w0 = wr[0], w1 = wr[1];
            float d = w0.x * h0.x + w0.y * h0.y + w0.z * h0.z + w0.w * h0.w +
                      w1.x * h1.x + w1.y * h1.y + w1.z * h1.z + w1.w * h1.w;
#pragma unroll
            for (int off = 1; off < 64; off <<= 1) d += __shfl_xor(d, off, 64);
            if (lane == 0) {
                d += bout[v];
                logl[v] = d;
                out[((size_t)cb * TT + t) * VV + v] = d;
            }
        }
        __syncthreads();

        if (w == 0) {  // argmax, numpy first-max tie-break
            float bv = logl[lane];
            int bi = lane;
            for (int v = lane + 64; v < VV; v += 64) {
                float x = logl[v];
                if (x > bv) { bv = x; bi = v; }
            }
#pragma unroll
            for (int off = 1; off < 64; off <<= 1) {
                float ov = __shfl_xor(bv, off, 64);
                int oi = __shfl_xor(bi, off, 64);
                if (ov > bv || (ov == bv && oi < bi)) { bv = ov; bi = oi; }
            }
            if (lane == 0) chout[cb] = bi;
        } else if (w == 1) {  // qb = h.v0 + s0
            float p = 0.f;
#pragma unroll
            for (int j = 0; j < 8; j++) {
                int k = lane + 64 * j;
                p += hl[k] * v0[k];
            }
#pragma unroll
            for (int off = 1; off < 64; off <<= 1) p += __shfl_xor(p, off, 64);
            if (lane == 0) qb[cb] = p + s0[0];
        }
    }

    // 5. qp quarter: c = quad*128 + (tid&127), k split 4 ways (kq = tid>>7)
    {
        int cl = tid & 127, kq = tid >> 7;
        int c = quad * 128 + cl;
        const float* Pp = P + (size_t)(kq * 128) * CC + c;
        float a = 0.f;
#pragma unroll 8
        for (int kk = 0; kk < 128; kk++)
            a += hl[kq * 128 + kk] * Pp[(size_t)kk * CC];
        red[kq * 128 + cl] = a;
    }
    __syncthreads();
    if (tid < 128) {
        int c = quad * 128 + tid;
        float r = red[tid] + red[128 + tid] + red[256 + tid] + red[384 + tid] + p0[c];
        qp[(size_t)cb * CC + c] = r;
    }
}

// ---------------------------------------------------------------------------

extern "C" void kernel_launch(void* const* d_in, const int* in_sizes, int n_in,
                              void* d_out, int out_size, void* d_ws, size_t ws_size,
                              hipStream_t stream) {
    const float* X    = (const float*)d_in[0];   // [64,1024,512]
    const int*   lab  = (const int*)d_in[1];     // [64,128]
    const float* Icw  = (const float*)d_in[2];   // [512,512]
    const float* Icb  = (const float*)d_in[3];   // [512]
    const float* Hcw  = (const float*)d_in[4];   // [512,512]
    const float* Hcb  = (const float*)d_in[5];   // [512]
    const float* Wih  = (const float*)d_in[6];   // [2048,652]
    const float* bih  = (const float*)d_in[7];   // [2048]
    const float* Whh  = (const float*)d_in[8];   // [2048,512]
    const float* bhh  = (const float*)d_in[9];   // [2048]
    const float* Wout = (const float*)d_in[10];  // [140,512]
    const float* bout = (const float*)d_in[11];  // [140]
    float* out = (float*)d_out;                  // [64,128,140]

    // workspace layout (floats)
    float* ws = (float*)d_ws;
    size_t off = 0;
    float* P        = ws + off; off += 512 * 512;
    float* GT       = ws + off; off += 512 * 2048;
    float* WhhT     = ws + off; off += 512 * 2048;
    float* Wih0T    = ws + off; off += 140 * 2048;
    float* gateb    = ws + off; off += 2048;
    float* p0       = ws + off; off += 512;
    float* v0       = ws + off; off += 512;
    float* s0       = ws + off; off += 64;
    float* h        = ws + off; off += 64 * 512;
    float* cstA     = ws + off; off += 64 * 512;
    float* cstB     = ws + off; off += 64 * 512;
    float* qp       = ws + off; off += 64 * 512;
    float* qb       = ws + off; off += 64;
    float* part_m   = ws + off; off += 64 * NCH;
    float* part_l   = ws + off; off += 64 * NCH;
    float* part_acc = ws + off; off += 64 * NCH * 512;
    float* pg       = ws + off; off += 8 * 64 * 2048;  // aliased as Gtmp in precompute
    int*   charrA   = (int*)(ws + off); off += 64;
    int*   charrB   = (int*)(ws + off); off += 64;
    if (ws_size < off * sizeof(float)) return;  // workspace too small -> fail loudly

    float* Gtmp = pg;  // reuse: Gtmp only live before first step

    // ---- one-time precompute ----
    k_small<<<1, 512, 0, stream>>>(Hcw, Hcb, Icw, Icb, p0, v0, s0);
    k_P<<<dim3(2, 512), 256, 0, stream>>>(Hcw, Icw, P);
    k_G<<<dim3(2, 256), 256, 0, stream>>>(Wih, Icw, Gtmp);
    k_transpose<<<dim3(16, 64), dim3(32, 8), 0, stream>>>(Gtmp, GT, 2048, 512, 512, 0);
    k_transpose<<<dim3(16, 64), dim3(32, 8), 0, stream>>>(Whh, WhhT, 2048, 512, 512, 0);
    k_transpose<<<dim3(5, 64), dim3(32, 8), 0, stream>>>(Wih, Wih0T, 2048, 140, 652, 0);
    k_gate_bias<<<8, 256, 0, stream>>>(Wih, Icb, bih, bhh, gateb);
    k_init<<<64, 512, 0, stream>>>(lab, p0, s0, h, cstA, qp, qb, charrA);

    // ---- sequential decode: 3 kernels/step, cst+charr ping-pong ----
    for (int t = 0; t < TT; t++) {
        const float* cin = (t & 1) ? cstB : cstA;
        float* cout      = (t & 1) ? cstA : cstB;
        const int* chin  = (t & 1) ? charrB : charrA;
        int* chout       = (t & 1) ? charrA : charrB;
        k_flash<<<dim3(NCH, 64), 512, 0, stream>>>(X, qp, qb, part_m, part_l, part_acc);
        k_gates<<<dim3(8, 8, 4), 512, 0, stream>>>(part_m, part_l, part_acc, h, GT, WhhT, pg);
        k_updqp<<<256, 512, 0, stream>>>(pg, gateb, Wih0T, Wout, bout, v0, s0, P, p0,
                                         cin, cout, chin, chout, h, qp, qb, out, t);
    }
}

// Round 11
// 7878.107 us; speedup vs baseline: 1.0847x; 1.0847x over previous
//
#include <hip/hip_runtime.h>
#include <math.h>

#define BB 64
#define SS 1024
#define CC 512
#define VV 140
#define AA 512
#define HH 512
#define TT 128
#define G4 2048   // 4*H
#define VA 652    // V+A
#define NCH 8     // flash S-chunks per batch

// ---------------------------------------------------------------------------
// One-time precompute kernels
// ---------------------------------------------------------------------------

// p0[c] = sum_a Hcb[a]*Ic[a][c]; v0[k] = sum_a Hc[a][k]*Icb[a]; s0 = Hcb.Icb
__global__ void k_small(const float* __restrict__ Hc, const float* __restrict__ Hcb,
                        const float* __restrict__ Ic, const float* __restrict__ Icb,
                        float* __restrict__ p0, float* __restrict__ v0,
                        float* __restrict__ s0) {
    int t = threadIdx.x;  // 512
    float av = 0.f, pv = 0.f;
    for (int a = 0; a < AA; a++) {
        av += Hc[a * HH + t] * Icb[a];
        pv += Hcb[a] * Ic[a * CC + t];
    }
    v0[t] = av;
    p0[t] = pv;
    if (t == 0) {
        float s = 0.f;
        for (int a = 0; a < AA; a++) s += Hcb[a] * Icb[a];
        s0[0] = s;
    }
}

// P[k][c] = sum_a Hc[a][k] * Ic[a][c]     (P = Hc^T Ic, [512][512])
__global__ __launch_bounds__(256) void k_P(const float* __restrict__ Hc,
                                           const float* __restrict__ Ic,
                                           float* __restrict__ P) {
    int k = blockIdx.y;
    int c = blockIdx.x * 256 + threadIdx.x;
    float acc = 0.f;
    for (int a = 0; a < AA; a++) acc += Hc[a * HH + k] * Ic[a * CC + c];
    P[k * CC + c] = acc;
}

// Gtmp[g][c] = sum_a Wih[g][140+a] * Ic[a][c]   ([2048][512])
__global__ __launch_bounds__(256) void k_G(const float* __restrict__ Wih,
                                           const float* __restrict__ Ic,
                                           float* __restrict__ Gtmp) {
    int gb = blockIdx.y * 8;
    int c = blockIdx.x * 256 + threadIdx.x;
    float acc[8];
#pragma unroll
    for (int j = 0; j < 8; j++) acc[j] = 0.f;
    for (int a = 0; a < AA; a++) {
        float ic = Ic[a * CC + c];
#pragma unroll
        for (int j = 0; j < 8; j++) acc[j] += Wih[(size_t)(gb + j) * VA + VV + a] * ic;
    }
#pragma unroll
    for (int j = 0; j < 8; j++) Gtmp[(size_t)(gb + j) * CC + c] = acc[j];
}

// gate_bias[g] = b_ih[g] + b_hh[g] + sum_a Wih[g][140+a]*Icb[a]
__global__ void k_gate_bias(const float* __restrict__ Wih, const float* __restrict__ Icb,
                            const float* __restrict__ bih, const float* __restrict__ bhh,
                            float* __restrict__ gate_bias) {
    int g = blockIdx.x * 256 + threadIdx.x;
    float acc = bih[g] + bhh[g];
    for (int a = 0; a < AA; a++) acc += Wih[(size_t)g * VA + VV + a] * Icb[a];
    gate_bias[g] = acc;
}

// dst[c*R + r] = src[r*ld + col0 + c]  (tiled transpose)
__global__ void k_transpose(const float* __restrict__ src, float* __restrict__ dst,
                            int R, int Cc, int ld, int col0) {
    __shared__ float tile[32][33];
    int r0 = blockIdx.y * 32, c0 = blockIdx.x * 32;
    int tx = threadIdx.x, ty = threadIdx.y;  // 32 x 8
#pragma unroll
    for (int k = 0; k < 4; k++) {
        int r = r0 + ty + k * 8, c = c0 + tx;
        if (r < R && c < Cc) tile[ty + k * 8][tx] = src[(size_t)r * ld + col0 + c];
    }
    __syncthreads();
#pragma unroll
    for (int k = 0; k < 4; k++) {
        int c = c0 + ty + k * 8, r = r0 + tx;
        if (c < Cc && r < R) dst[(size_t)c * R + r] = tile[tx][ty + k * 8];
    }
}

// h=c=0, q' = p0, qb = s0, char = labels[:,0]
__global__ void k_init(const int* __restrict__ labels, const float* __restrict__ p0,
                       const float* __restrict__ s0, float* __restrict__ h,
                       float* __restrict__ cstA, float* __restrict__ qp,
                       float* __restrict__ qb, int* __restrict__ charrA) {
    int b = blockIdx.x, t = threadIdx.x;  // 64 x 512
    h[b * HH + t] = 0.f;
    cstA[b * HH + t] = 0.f;
    qp[b * CC + t] = p0[t];
    if (t == 0) {
        qb[b] = s0[0];
        charrA[b] = labels[b * TT];
    }
}

// ---------------------------------------------------------------------------
// Per-step kernels
// ---------------------------------------------------------------------------

#define ONLINE_UPDATE(score, xv)                                      \
    if ((score) > m) {                                                \
        float f_ = expf(m - (score));                                 \
        l = l * f_ + 1.f;                                             \
        _Pragma("unroll")                                             \
        for (int j = 0; j < 8; j++) acc[j] = acc[j] * f_ + (xv)[j];   \
        m = (score);                                                  \
    } else {                                                          \
        float p_ = expf((score) - m);                                 \
        l += p_;                                                      \
        _Pragma("unroll")                                             \
        for (int j = 0; j < 8; j++) acc[j] += p_ * (xv)[j];           \
    }

#define DOT8(xv) ((xv)[0] * qa.x + (xv)[1] * qa.y + (xv)[2] * qa.z + (xv)[3] * qa.w + \
                  (xv)[4] * qb4.x + (xv)[5] * qb4.y + (xv)[6] * qb4.z + (xv)[7] * qb4.w)

#define UNPACK8(xv, ra, rb) \
    (xv)[0] = ra.x; (xv)[1] = ra.y; (xv)[2] = ra.z; (xv)[3] = ra.w; \
    (xv)[4] = rb.x; (xv)[5] = rb.y; (xv)[6] = rb.z; (xv)[7] = rb.w;

// Flash attention pass over X. grid (NCH=8 chunks, 64 b), 512 threads (8 waves)
// = 512 blocks (2/CU). Plain cached loads: X (128 MiB) is L3-resident across
// steps — round 9 measured that bypassing L3 (nontemporal) costs ~6 µs/step.
__global__ __launch_bounds__(512) void k_flash(const float* __restrict__ X,
                                               const float* __restrict__ qp,
                                               const float* __restrict__ qb,
                                               float* __restrict__ part_m,
                                               float* __restrict__ part_l,
                                               float* __restrict__ part_acc) {
    int b = blockIdx.y, chunk = blockIdx.x;
    int tid = threadIdx.x, w = tid >> 6, lane = tid & 63;
    const float inv_sqrt_a = 0.044194173824159216f;  // 1/sqrt(512)

    const float4* q4 = (const float4*)(qp + b * CC) + lane * 2;
    float4 qa = q4[0], qb4 = q4[1];
    float qoff = qb[b];

    float m = -INFINITY, l = 0.f;
    float acc[8];
#pragma unroll
    for (int j = 0; j < 8; j++) acc[j] = 0.f;

    int s0 = chunk * 128 + w * 16;
    const float* base = X + ((size_t)b * SS + s0) * CC;
    for (int i = 0; i < 16; i += 4) {
        const float4* xr0 = (const float4*)(base + (size_t)(i + 0) * CC) + lane * 2;
        const float4* xr1 = (const float4*)(base + (size_t)(i + 1) * CC) + lane * 2;
        const float4* xr2 = (const float4*)(base + (size_t)(i + 2) * CC) + lane * 2;
        const float4* xr3 = (const float4*)(base + (size_t)(i + 3) * CC) + lane * 2;
        float4 x0a = xr0[0], x0b = xr0[1];
        float4 x1a = xr1[0], x1b = xr1[1];
        float4 x2a = xr2[0], x2b = xr2[1];
        float4 x3a = xr3[0], x3b = xr3[1];
        float xv0[8], xv1[8], xv2[8], xv3[8];
        UNPACK8(xv0, x0a, x0b);
        UNPACK8(xv1, x1a, x1b);
        UNPACK8(xv2, x2a, x2b);
        UNPACK8(xv3, x3a, x3b);
        float d0 = DOT8(xv0);
        float d1 = DOT8(xv1);
        float d2 = DOT8(xv2);
        float d3 = DOT8(xv3);
#pragma unroll
        for (int off = 1; off < 64; off <<= 1) {
            d0 += __shfl_xor(d0, off, 64);
            d1 += __shfl_xor(d1, off, 64);
            d2 += __shfl_xor(d2, off, 64);
            d3 += __shfl_xor(d3, off, 64);
        }
        float sc0 = (d0 + qoff) * inv_sqrt_a;
        float sc1 = (d1 + qoff) * inv_sqrt_a;
        float sc2 = (d2 + qoff) * inv_sqrt_a;
        float sc3 = (d3 + qoff) * inv_sqrt_a;
        ONLINE_UPDATE(sc0, xv0);
        ONLINE_UPDATE(sc1, xv1);
        ONLINE_UPDATE(sc2, xv2);
        ONLINE_UPDATE(sc3, xv3);
    }

    // combine 8 waves -> one block partial
    __shared__ float lm[8], ll[8];
    __shared__ __align__(16) float lacc[8][512];
    if (lane == 0) lm[w] = m;
    __syncthreads();
    float M = lm[0];
#pragma unroll
    for (int j = 1; j < 8; j++) M = fmaxf(M, lm[j]);
    float f = expf(m - M);
    if (lane == 0) ll[w] = l * f;
#pragma unroll
    for (int j = 0; j < 8; j++) lacc[w][lane * 8 + j] = acc[j] * f;
    __syncthreads();
    float s = 0.f;
#pragma unroll
    for (int j = 0; j < 8; j++) s += lacc[j][tid];
    part_acc[((b * NCH + chunk) << 9) + tid] = s;
    if (tid == 0) {
        float lt = 0.f;
        for (int j = 0; j < 8; j++) lt += ll[j];
        part_m[b * NCH + chunk] = M;
        part_l[b * NCH + chunk] = lt;
    }
}

// Skinny GEMM: pg[cs][b][g] partial of  ywx.G^T (cs 0..3)  or  h.Whh^T (cs 4..7).
// grid (cs=8, gt=8, bt=4), 512 threads; thread = 2b x 4g tile.
// W is STREAMED directly from global in the FMA loop (no LDS wbuf, 1 barrier
// instead of 8): each wave's W row-slice read is 1 KB coalesced and identical
// across the 8 waves (L1 broadcast); the 4 bt-blocks share tiles via L2.
// i ascends 0..127 = old cchunk*32+i order -> per-output FMA chain unchanged.
__global__ __launch_bounds__(512) void k_gates(const float* __restrict__ part_m,
                                               const float* __restrict__ part_l,
                                               const float* __restrict__ part_acc,
                                               const float* __restrict__ h,
                                               const float* __restrict__ GT,
                                               const float* __restrict__ WhhT,
                                               float* __restrict__ pg) {
    int cs = blockIdx.x, gt = blockIdx.y, bt = blockIdx.z;
    int tid = threadIdx.x;
    int tg = tid & 63, tb = tid >> 6;  // tg: 64 col-groups of 4; tb: 8 b-pairs

    __shared__ __align__(16) float actT[128 * 16];  // [cc][bb]
    __shared__ float coefL[16][NCH];

    if (cs < 4) {
        if (tid < 16) {
            int b = bt * 16 + tid;
            float mv[NCH];
#pragma unroll
            for (int i = 0; i < NCH; i++) mv[i] = part_m[b * NCH + i];
            float M = mv[0];
#pragma unroll
            for (int i = 1; i < NCH; i++) M = fmaxf(M, mv[i]);
            float denom = 0.f;
            float ev[NCH];
#pragma unroll
            for (int i = 0; i < NCH; i++) {
                ev[i] = expf(mv[i] - M);
                denom += ev[i] * part_l[b * NCH + i];
            }
            float inv = 1.f / denom;
#pragma unroll
            for (int i = 0; i < NCH; i++) coefL[tid][i] = ev[i] * inv;
        }
        __syncthreads();
#pragma unroll
        for (int k = 0; k < 4; k++) {
            int idx = k * 512 + tid;
            int bb = idx >> 7, cc = idx & 127;
            int b = bt * 16 + bb;
            const float* pa = part_acc + (size_t)(b * NCH) * 512 + cs * 128 + cc;
            float v = 0.f;
#pragma unroll
            for (int i = 0; i < NCH; i++) v += coefL[bb][i] * pa[(size_t)i * 512];
            actT[cc * 16 + bb] = v;
        }
    } else {
#pragma unroll
        for (int k = 0; k < 4; k++) {
            int idx = k * 512 + tid;
            int bb = idx >> 7, cc = idx & 127;
            actT[cc * 16 + bb] = h[(bt * 16 + bb) * HH + (cs - 4) * 128 + cc];
        }
    }
    __syncthreads();

    const float* W = (cs < 4) ? (GT + (size_t)(cs * 128) * G4)
                              : (WhhT + (size_t)((cs - 4) * 128) * G4);
    const float* Wp = W + gt * 256 + tg * 4;
    float4 acc0 = make_float4(0, 0, 0, 0), acc1 = make_float4(0, 0, 0, 0);

#define FMA4(accv, sclr, wv)                    \
    accv.x += (sclr) * wv.x; accv.y += (sclr) * wv.y; \
    accv.z += (sclr) * wv.z; accv.w += (sclr) * wv.w;

#pragma unroll 8
    for (int i = 0; i < 128; i++) {
        float4 wv = *(const float4*)&Wp[(size_t)i * G4];
        float2 av = *(const float2*)&actT[i * 16 + tb * 2];
        FMA4(acc0, av.x, wv);
        FMA4(acc1, av.y, wv);
    }
#undef FMA4

    int b0 = bt * 16 + tb * 2;
    int g0 = gt * 256 + tg * 4;
    *(float4*)&pg[(size_t)(cs * BB + b0 + 0) * G4 + g0] = acc0;
    *(float4*)&pg[(size_t)(cs * BB + b0 + 1) * G4 + g0] = acc1;
}

// Fused update + qp. grid 256 blocks (b = bx>>2, quad = bx&3), 512 threads.
// All 4 quad-blocks of a batch redundantly compute gates+LSTM; quad 0 also
// does logits/argmax/out/qb and writes h/cst; every quad computes its
// 128-column quarter of next-step qp. cst/charr double-buffered (no races).
__global__ __launch_bounds__(512) void k_updqp(
    const float* __restrict__ pg, const float* __restrict__ gate_bias,
    const float* __restrict__ Wih0T, const float* __restrict__ Wout,
    const float* __restrict__ bout, const float* __restrict__ v0,
    const float* __restrict__ s0, const float* __restrict__ P,
    const float* __restrict__ p0,
    const float* __restrict__ cin, float* __restrict__ cout,
    const int* __restrict__ chin, int* __restrict__ chout,
    float* __restrict__ h, float* __restrict__ qp, float* __restrict__ qb,
    float* __restrict__ out, int t) {
    int bx = blockIdx.x, tid = threadIdx.x;
    int cb = bx >> 2, quad = bx & 3;
    int w = tid >> 6, lane = tid & 63;

    __shared__ __align__(16) float gl[G4];
    __shared__ __align__(16) float hl[HH];
    __shared__ float logl[VV];
    __shared__ float red[512];

    int ch = chin[cb];

    // 1. gates: g0 = tid*4; order: bias + Wih0T[ch] + pg j=0..7
    {
        int g0 = tid * 4;
        float4 a = *(const float4*)&gate_bias[g0];
        float4 wv = *(const float4*)&Wih0T[(size_t)ch * G4 + g0];
        a.x += wv.x; a.y += wv.y; a.z += wv.z; a.w += wv.w;
#pragma unroll
        for (int j = 0; j < 8; j++) {
            float4 p = *(const float4*)&pg[(size_t)(j * BB + cb) * G4 + g0];
            a.x += p.x; a.y += p.y; a.z += p.z; a.w += p.w;
        }
        *(float4*)&gl[g0] = a;
    }
    __syncthreads();

    // 2. LSTM cell (c-state ping-pong: read cin, write cout)
    {
        float ig = 1.f / (1.f + expf(-gl[tid]));
        float fg = 1.f / (1.f + expf(-gl[512 + tid]));
        float gg = tanhf(gl[1024 + tid]);
        float og = 1.f / (1.f + expf(-gl[1536 + tid]));
        float cn = fg * cin[cb * HH + tid] + ig * gg;
        float hn = og * tanhf(cn);
        if (quad == 0) {
            cout[cb * HH + tid] = cn;
            h[cb * HH + tid] = hn;
        }
        hl[tid] = hn;
    }
    __syncthreads();

    // 3+4. logits / argmax / out / qb: quad 0 only (block-uniform branch)
    if (quad == 0) {
        const float4* hr = (const float4*)hl + lane * 2;
        float4 h0 = hr[0], h1 = hr[1];
        for (int v = w; v < VV; v += 8) {
            const float4* wr = (const float4*)(Wout + (size_t)v * HH) + lane * 2;
            float4 w0 = wr[0], w1 = wr[1];
            float d = w0.x * h0.x + w0.y * h0.y + w0.z * h0.z + w0.w * h0.w +
                      w1.x * h1.x + w1.y * h1.y + w1.z * h1.z + w1.w * h1.w;
#pragma unroll
            for (int off = 1; off < 64; off <<= 1) d += __shfl_xor(d, off, 64);
            if (lane == 0) {
                d += bout[v];
                logl[v] = d;
                out[((size_t)cb * TT + t) * VV + v] = d;
            }
        }
        __syncthreads();

        if (w == 0) {  // argmax, numpy first-max tie-break
            float bv = logl[lane];
            int bi = lane;
            for (int v = lane + 64; v < VV; v += 64) {
                float x = logl[v];
                if (x > bv) { bv = x; bi = v; }
            }
#pragma unroll
            for (int off = 1; off < 64; off <<= 1) {
                float ov = __shfl_xor(bv, off, 64);
                int oi = __shfl_xor(bi, off, 64);
                if (ov > bv || (ov == bv && oi < bi)) { bv = ov; bi = oi; }
            }
            if (lane == 0) chout[cb] = bi;
        } else if (w == 1) {  // qb = h.v0 + s0
            float p = 0.f;
#pragma unroll
            for (int j = 0; j < 8; j++) {
                int k = lane + 64 * j;
                p += hl[k] * v0[k];
            }
#pragma unroll
            for (int off = 1; off < 64; off <<= 1) p += __shfl_xor(p, off, 64);
            if (lane == 0) qb[cb] = p + s0[0];
        }
    }

    // 5. qp quarter: c = quad*128 + (tid&127), k split 4 ways (kq = tid>>7)
    {
        int cl = tid & 127, kq = tid >> 7;
        int c = quad * 128 + cl;
        const float* Pp = P + (size_t)(kq * 128) * CC + c;
        float a = 0.f;
#pragma unroll 8
        for (int kk = 0; kk < 128; kk++)
            a += hl[kq * 128 + kk] * Pp[(size_t)kk * CC];
        red[kq * 128 + cl] = a;
    }
    __syncthreads();
    if (tid < 128) {
        int c = quad * 128 + tid;
        float r = red[tid] + red[128 + tid] + red[256 + tid] + red[384 + tid] + p0[c];
        qp[(size_t)cb * CC + c] = r;
    }
}

// ---------------------------------------------------------------------------

extern "C" void kernel_launch(void* const* d_in, const int* in_sizes, int n_in,
                              void* d_out, int out_size, void* d_ws, size_t ws_size,
                              hipStream_t stream) {
    const float* X    = (const float*)d_in[0];   // [64,1024,512]
    const int*   lab  = (const int*)d_in[1];     // [64,128]
    const float* Icw  = (const float*)d_in[2];   // [512,512]
    const float* Icb  = (const float*)d_in[3];   // [512]
    const float* Hcw  = (const float*)d_in[4];   // [512,512]
    const float* Hcb  = (const float*)d_in[5];   // [512]
    const float* Wih  = (const float*)d_in[6];   // [2048,652]
    const float* bih  = (const float*)d_in[7];   // [2048]
    const float* Whh  = (const float*)d_in[8];   // [2048,512]
    const float* bhh  = (const float*)d_in[9];   // [2048]
    const float* Wout = (const float*)d_in[10];  // [140,512]
    const float* bout = (const float*)d_in[11];  // [140]
    float* out = (float*)d_out;                  // [64,128,140]

    // workspace layout (floats)
    float* ws = (float*)d_ws;
    size_t off = 0;
    float* P        = ws + off; off += 512 * 512;
    float* GT       = ws + off; off += 512 * 2048;
    float* WhhT     = ws + off; off += 512 * 2048;
    float* Wih0T    = ws + off; off += 140 * 2048;
    float* gateb    = ws + off; off += 2048;
    float* p0       = ws + off; off += 512;
    float* v0       = ws + off; off += 512;
    float* s0       = ws + off; off += 64;
    float* h        = ws + off; off += 64 * 512;
    float* cstA     = ws + off; off += 64 * 512;
    float* cstB     = ws + off; off += 64 * 512;
    float* qp       = ws + off; off += 64 * 512;
    float* qb       = ws + off; off += 64;
    float* part_m   = ws + off; off += 64 * NCH;
    float* part_l   = ws + off; off += 64 * NCH;
    float* part_acc = ws + off; off += 64 * NCH * 512;
    float* pg       = ws + off; off += 8 * 64 * 2048;  // aliased as Gtmp in precompute
    int*   charrA   = (int*)(ws + off); off += 64;
    int*   charrB   = (int*)(ws + off); off += 64;
    if (ws_size < off * sizeof(float)) return;  // workspace too small -> fail loudly

    float* Gtmp = pg;  // reuse: Gtmp only live before first step

    // ---- one-time precompute ----
    k_small<<<1, 512, 0, stream>>>(Hcw, Hcb, Icw, Icb, p0, v0, s0);
    k_P<<<dim3(2, 512), 256, 0, stream>>>(Hcw, Icw, P);
    k_G<<<dim3(2, 256), 256, 0, stream>>>(Wih, Icw, Gtmp);
    k_transpose<<<dim3(16, 64), dim3(32, 8), 0, stream>>>(Gtmp, GT, 2048, 512, 512, 0);
    k_transpose<<<dim3(16, 64), dim3(32, 8), 0, stream>>>(Whh, WhhT, 2048, 512, 512, 0);
    k_transpose<<<dim3(5, 64), dim3(32, 8), 0, stream>>>(Wih, Wih0T, 2048, 140, 652, 0);
    k_gate_bias<<<8, 256, 0, stream>>>(Wih, Icb, bih, bhh, gateb);
    k_init<<<64, 512, 0, stream>>>(lab, p0, s0, h, cstA, qp, qb, charrA);

    // ---- sequential decode: 3 kernels/step, cst+charr ping-pong ----
    for (int t = 0; t < TT; t++) {
        const float* cin = (t & 1) ? cstB : cstA;
        float* cout      = (t & 1) ? cstA : cstB;
        const int* chin  = (t & 1) ? charrB : charrA;
        int* chout       = (t & 1) ? charrA : charrB;
        k_flash<<<dim3(NCH, 64), 512, 0, stream>>>(X, qp, qb, part_m, part_l, part_acc);
        k_gates<<<dim3(8, 8, 4), 512, 0, stream>>>(part_m, part_l, part_acc, h, GT, WhhT, pg);
        k_updqp<<<256, 512, 0, stream>>>(pg, gateb, Wih0T, Wout, bout, v0, s0, P, p0,
                                         cin, cout, chin, chout, h, qp, qb, out, t);
    }
}

// Round 12
// 7788.439 us; speedup vs baseline: 1.0972x; 1.0115x over previous
//
#include <hip/hip_runtime.h>
#include <math.h>

#define BB 64
#define SS 1024
#define CC 512
#define VV 140
#define AA 512
#define HH 512
#define TT 128
#define G4 2048   // 4*H
#define VA 652    // V+A
#define NCH 8     // flash S-chunks per batch

// ---------------------------------------------------------------------------
// One-time precompute kernels
// ---------------------------------------------------------------------------

// p0[c] = sum_a Hcb[a]*Ic[a][c]; v0[k] = sum_a Hc[a][k]*Icb[a]; s0 = Hcb.Icb
__global__ void k_small(const float* __restrict__ Hc, const float* __restrict__ Hcb,
                        const float* __restrict__ Ic, const float* __restrict__ Icb,
                        float* __restrict__ p0, float* __restrict__ v0,
                        float* __restrict__ s0) {
    int t = threadIdx.x;  // 512
    float av = 0.f, pv = 0.f;
    for (int a = 0; a < AA; a++) {
        av += Hc[a * HH + t] * Icb[a];
        pv += Hcb[a] * Ic[a * CC + t];
    }
    v0[t] = av;
    p0[t] = pv;
    if (t == 0) {
        float s = 0.f;
        for (int a = 0; a < AA; a++) s += Hcb[a] * Icb[a];
        s0[0] = s;
    }
}

// P[k][c] = sum_a Hc[a][k] * Ic[a][c]     (P = Hc^T Ic, [512][512])
__global__ __launch_bounds__(256) void k_P(const float* __restrict__ Hc,
                                           const float* __restrict__ Ic,
                                           float* __restrict__ P) {
    int k = blockIdx.y;
    int c = blockIdx.x * 256 + threadIdx.x;
    float acc = 0.f;
    for (int a = 0; a < AA; a++) acc += Hc[a * HH + k] * Ic[a * CC + c];
    P[k * CC + c] = acc;
}

// Gtmp[g][c] = sum_a Wih[g][140+a] * Ic[a][c]   ([2048][512])
__global__ __launch_bounds__(256) void k_G(const float* __restrict__ Wih,
                                           const float* __restrict__ Ic,
                                           float* __restrict__ Gtmp) {
    int gb = blockIdx.y * 8;
    int c = blockIdx.x * 256 + threadIdx.x;
    float acc[8];
#pragma unroll
    for (int j = 0; j < 8; j++) acc[j] = 0.f;
    for (int a = 0; a < AA; a++) {
        float ic = Ic[a * CC + c];
#pragma unroll
        for (int j = 0; j < 8; j++) acc[j] += Wih[(size_t)(gb + j) * VA + VV + a] * ic;
    }
#pragma unroll
    for (int j = 0; j < 8; j++) Gtmp[(size_t)(gb + j) * CC + c] = acc[j];
}

// gate_bias[g] = b_ih[g] + b_hh[g] + sum_a Wih[g][140+a]*Icb[a]
__global__ void k_gate_bias(const float* __restrict__ Wih, const float* __restrict__ Icb,
                            const float* __restrict__ bih, const float* __restrict__ bhh,
                            float* __restrict__ gate_bias) {
    int g = blockIdx.x * 256 + threadIdx.x;
    float acc = bih[g] + bhh[g];
    for (int a = 0; a < AA; a++) acc += Wih[(size_t)g * VA + VV + a] * Icb[a];
    gate_bias[g] = acc;
}

// dst[c*R + r] = src[r*ld + col0 + c]  (tiled transpose)
__global__ void k_transpose(const float* __restrict__ src, float* __restrict__ dst,
                            int R, int Cc, int ld, int col0) {
    __shared__ float tile[32][33];
    int r0 = blockIdx.y * 32, c0 = blockIdx.x * 32;
    int tx = threadIdx.x, ty = threadIdx.y;  // 32 x 8
#pragma unroll
    for (int k = 0; k < 4; k++) {
        int r = r0 + ty + k * 8, c = c0 + tx;
        if (r < R && c < Cc) tile[ty + k * 8][tx] = src[(size_t)r * ld + col0 + c];
    }
    __syncthreads();
#pragma unroll
    for (int k = 0; k < 4; k++) {
        int c = c0 + ty + k * 8, r = r0 + tx;
        if (c < Cc && r < R) dst[(size_t)c * R + r] = tile[tx][ty + k * 8];
    }
}

// h=c=0, q' = p0, qb = s0, char = labels[:,0]
__global__ void k_init(const int* __restrict__ labels, const float* __restrict__ p0,
                       const float* __restrict__ s0, float* __restrict__ h,
                       float* __restrict__ cstA, float* __restrict__ qp,
                       float* __restrict__ qb, int* __restrict__ charrA) {
    int b = blockIdx.x, t = threadIdx.x;  // 64 x 512
    h[b * HH + t] = 0.f;
    cstA[b * HH + t] = 0.f;
    qp[b * CC + t] = p0[t];
    if (t == 0) {
        qb[b] = s0[0];
        charrA[b] = labels[b * TT];
    }
}

// ---------------------------------------------------------------------------
// Per-step kernels
// ---------------------------------------------------------------------------

#define ONLINE_UPDATE(score, xv)                                      \
    if ((score) > m) {                                                \
        float f_ = expf(m - (score));                                 \
        l = l * f_ + 1.f;                                             \
        _Pragma("unroll")                                             \
        for (int j = 0; j < 8; j++) acc[j] = acc[j] * f_ + (xv)[j];   \
        m = (score);                                                  \
    } else {                                                          \
        float p_ = expf((score) - m);                                 \
        l += p_;                                                      \
        _Pragma("unroll")                                             \
        for (int j = 0; j < 8; j++) acc[j] += p_ * (xv)[j];           \
    }

#define DOT8(xv) ((xv)[0] * qa.x + (xv)[1] * qa.y + (xv)[2] * qa.z + (xv)[3] * qa.w + \
                  (xv)[4] * qb4.x + (xv)[5] * qb4.y + (xv)[6] * qb4.z + (xv)[7] * qb4.w)

#define UNPACK8(xv, ra, rb) \
    (xv)[0] = ra.x; (xv)[1] = ra.y; (xv)[2] = ra.z; (xv)[3] = ra.w; \
    (xv)[4] = rb.x; (xv)[5] = rb.y; (xv)[6] = rb.z; (xv)[7] = rb.w;

// Flash attention pass over X. grid (NCH=8 chunks, 64 b), 512 threads (8 waves).
// STEP-ALTERNATING SCAN DIRECTION: on odd steps the block->(b,chunk) map is
// reversed, so step t+1 first touches the X lines step t cached last. X scans
// cyclically through the 256 MiB L3 (128 MiB/step, measured 66 MB/step HBM
// misses = LRU thrash); alternating direction converts those misses to hits.
// Pure block remap -> results bit-identical per (b,chunk).
__global__ __launch_bounds__(512) void k_flash(const float* __restrict__ X,
                                               const float* __restrict__ qp,
                                               const float* __restrict__ qb,
                                               float* __restrict__ part_m,
                                               float* __restrict__ part_l,
                                               float* __restrict__ part_acc,
                                               int t) {
    int b = blockIdx.y, chunk = blockIdx.x;
    if (t & 1) { b = BB - 1 - b; chunk = NCH - 1 - chunk; }
    int tid = threadIdx.x, w = tid >> 6, lane = tid & 63;
    const float inv_sqrt_a = 0.044194173824159216f;  // 1/sqrt(512)

    const float4* q4 = (const float4*)(qp + b * CC) + lane * 2;
    float4 qa = q4[0], qb4 = q4[1];
    float qoff = qb[b];

    float m = -INFINITY, l = 0.f;
    float acc[8];
#pragma unroll
    for (int j = 0; j < 8; j++) acc[j] = 0.f;

    int s0 = chunk * 128 + w * 16;
    const float* base = X + ((size_t)b * SS + s0) * CC;
    for (int i = 0; i < 16; i += 4) {
        const float4* xr0 = (const float4*)(base + (size_t)(i + 0) * CC) + lane * 2;
        const float4* xr1 = (const float4*)(base + (size_t)(i + 1) * CC) + lane * 2;
        const float4* xr2 = (const float4*)(base + (size_t)(i + 2) * CC) + lane * 2;
        const float4* xr3 = (const float4*)(base + (size_t)(i + 3) * CC) + lane * 2;
        float4 x0a = xr0[0], x0b = xr0[1];
        float4 x1a = xr1[0], x1b = xr1[1];
        float4 x2a = xr2[0], x2b = xr2[1];
        float4 x3a = xr3[0], x3b = xr3[1];
        float xv0[8], xv1[8], xv2[8], xv3[8];
        UNPACK8(xv0, x0a, x0b);
        UNPACK8(xv1, x1a, x1b);
        UNPACK8(xv2, x2a, x2b);
        UNPACK8(xv3, x3a, x3b);
        float d0 = DOT8(xv0);
        float d1 = DOT8(xv1);
        float d2 = DOT8(xv2);
        float d3 = DOT8(xv3);
#pragma unroll
        for (int off = 1; off < 64; off <<= 1) {
            d0 += __shfl_xor(d0, off, 64);
            d1 += __shfl_xor(d1, off, 64);
            d2 += __shfl_xor(d2, off, 64);
            d3 += __shfl_xor(d3, off, 64);
        }
        float sc0 = (d0 + qoff) * inv_sqrt_a;
        float sc1 = (d1 + qoff) * inv_sqrt_a;
        float sc2 = (d2 + qoff) * inv_sqrt_a;
        float sc3 = (d3 + qoff) * inv_sqrt_a;
        ONLINE_UPDATE(sc0, xv0);
        ONLINE_UPDATE(sc1, xv1);
        ONLINE_UPDATE(sc2, xv2);
        ONLINE_UPDATE(sc3, xv3);
    }

    // combine 8 waves -> one block partial
    __shared__ float lm[8], ll[8];
    __shared__ __align__(16) float lacc[8][512];
    if (lane == 0) lm[w] = m;
    __syncthreads();
    float M = lm[0];
#pragma unroll
    for (int j = 1; j < 8; j++) M = fmaxf(M, lm[j]);
    float f = expf(m - M);
    if (lane == 0) ll[w] = l * f;
#pragma unroll
    for (int j = 0; j < 8; j++) lacc[w][lane * 8 + j] = acc[j] * f;
    __syncthreads();
    float s = 0.f;
#pragma unroll
    for (int j = 0; j < 8; j++) s += lacc[j][tid];
    part_acc[((b * NCH + chunk) << 9) + tid] = s;
    if (tid == 0) {
        float lt = 0.f;
        for (int j = 0; j < 8; j++) lt += ll[j];
        part_m[b * NCH + chunk] = M;
        part_l[b * NCH + chunk] = lt;
    }
}

// Skinny GEMM: pg[cs][b][g] partial of  ywx.G^T (cs 0..3)  or  h.Whh^T (cs 4..7).
// grid (cs=8, gt=8, bt=4), 512 threads (2 blocks/CU); thread = 2b x 4g tile.
// (round-7 wbuf version — the best-measured gates variant)
__global__ __launch_bounds__(512) void k_gates(const float* __restrict__ part_m,
                                               const float* __restrict__ part_l,
                                               const float* __restrict__ part_acc,
                                               const float* __restrict__ h,
                                               const float* __restrict__ GT,
                                               const float* __restrict__ WhhT,
                                               float* __restrict__ pg) {
    int cs = blockIdx.x, gt = blockIdx.y, bt = blockIdx.z;
    int tid = threadIdx.x;
    int tg = tid & 63, tb = tid >> 6;  // tg: 64 col-groups of 4; tb: 8 b-pairs

    __shared__ __align__(16) float actT[128 * 16];  // [cc][bb]
    __shared__ float coefL[16][NCH];
    __shared__ __align__(16) float wbuf[32 * 256];

    if (cs < 4) {
        if (tid < 16) {
            int b = bt * 16 + tid;
            float mv[NCH];
#pragma unroll
            for (int i = 0; i < NCH; i++) mv[i] = part_m[b * NCH + i];
            float M = mv[0];
#pragma unroll
            for (int i = 1; i < NCH; i++) M = fmaxf(M, mv[i]);
            float denom = 0.f;
            float ev[NCH];
#pragma unroll
            for (int i = 0; i < NCH; i++) {
                ev[i] = expf(mv[i] - M);
                denom += ev[i] * part_l[b * NCH + i];
            }
            float inv = 1.f / denom;
#pragma unroll
            for (int i = 0; i < NCH; i++) coefL[tid][i] = ev[i] * inv;
        }
        __syncthreads();
#pragma unroll
        for (int k = 0; k < 4; k++) {
            int idx = k * 512 + tid;
            int bb = idx >> 7, cc = idx & 127;
            int b = bt * 16 + bb;
            const float* pa = part_acc + (size_t)(b * NCH) * 512 + cs * 128 + cc;
            float v = 0.f;
#pragma unroll
            for (int i = 0; i < NCH; i++) v += coefL[bb][i] * pa[(size_t)i * 512];
            actT[cc * 16 + bb] = v;
        }
    } else {
#pragma unroll
        for (int k = 0; k < 4; k++) {
            int idx = k * 512 + tid;
            int bb = idx >> 7, cc = idx & 127;
            actT[cc * 16 + bb] = h[(bt * 16 + bb) * HH + (cs - 4) * 128 + cc];
        }
    }

    const float* W = (cs < 4) ? (GT + (size_t)(cs * 128) * G4)
                              : (WhhT + (size_t)((cs - 4) * 128) * G4);
    float4 acc0 = make_float4(0, 0, 0, 0), acc1 = make_float4(0, 0, 0, 0);

#define FMA4(accv, sclr, wv)                    \
    accv.x += (sclr) * wv.x; accv.y += (sclr) * wv.y; \
    accv.z += (sclr) * wv.z; accv.w += (sclr) * wv.w;

    for (int cchunk = 0; cchunk < 4; cchunk++) {
        __syncthreads();
#pragma unroll
        for (int k = 0; k < 16; k++) {
            int idx = k * 512 + tid;
            int i = idx >> 8, j = idx & 255;
            wbuf[idx] = W[(size_t)(cchunk * 32 + i) * G4 + gt * 256 + j];
        }
        __syncthreads();
#pragma unroll 4
        for (int i = 0; i < 32; i++) {
            float4 wv = *(const float4*)&wbuf[i * 256 + tg * 4];
            float2 av = *(const float2*)&actT[(cchunk * 32 + i) * 16 + tb * 2];
            FMA4(acc0, av.x, wv);
            FMA4(acc1, av.y, wv);
        }
    }
#undef FMA4

    int b0 = bt * 16 + tb * 2;
    int g0 = gt * 256 + tg * 4;
    *(float4*)&pg[(size_t)(cs * BB + b0 + 0) * G4 + g0] = acc0;
    *(float4*)&pg[(size_t)(cs * BB + b0 + 1) * G4 + g0] = acc1;
}

// Fused update + qp. grid 256 blocks (b = bx>>2, quad = bx&3), 512 threads.
// All 4 quad-blocks of a batch redundantly compute gates+LSTM; quad 0 also
// does logits/argmax/out/qb and writes h/cst; every quad computes its
// 128-column quarter of next-step qp. cst/charr double-buffered (no races).
__global__ __launch_bounds__(512) void k_updqp(
    const float* __restrict__ pg, const float* __restrict__ gate_bias,
    const float* __restrict__ Wih0T, const float* __restrict__ Wout,
    const float* __restrict__ bout, const float* __restrict__ v0,
    const float* __restrict__ s0, const float* __restrict__ P,
    const float* __restrict__ p0,
    const float* __restrict__ cin, float* __restrict__ cout,
    const int* __restrict__ chin, int* __restrict__ chout,
    float* __restrict__ h, float* __restrict__ qp, float* __restrict__ qb,
    float* __restrict__ out, int t) {
    int bx = blockIdx.x, tid = threadIdx.x;
    int cb = bx >> 2, quad = bx & 3;
    int w = tid >> 6, lane = tid & 63;

    __shared__ __align__(16) float gl[G4];
    __shared__ __align__(16) float hl[HH];
    __shared__ float logl[VV];
    __shared__ float red[512];

    int ch = chin[cb];

    // 1. gates: g0 = tid*4; order: bias + Wih0T[ch] + pg j=0..7
    {
        int g0 = tid * 4;
        float4 a = *(const float4*)&gate_bias[g0];
        float4 wv = *(const float4*)&Wih0T[(size_t)ch * G4 + g0];
        a.x += wv.x; a.y += wv.y; a.z += wv.z; a.w += wv.w;
#pragma unroll
        for (int j = 0; j < 8; j++) {
            float4 p = *(const float4*)&pg[(size_t)(j * BB + cb) * G4 + g0];
            a.x += p.x; a.y += p.y; a.z += p.z; a.w += p.w;
        }
        *(float4*)&gl[g0] = a;
    }
    __syncthreads();

    // 2. LSTM cell (c-state ping-pong: read cin, write cout)
    {
        float ig = 1.f / (1.f + expf(-gl[tid]));
        float fg = 1.f / (1.f + expf(-gl[512 + tid]));
        float gg = tanhf(gl[1024 + tid]);
        float og = 1.f / (1.f + expf(-gl[1536 + tid]));
        float cn = fg * cin[cb * HH + tid] + ig * gg;
        float hn = og * tanhf(cn);
        if (quad == 0) {
            cout[cb * HH + tid] = cn;
            h[cb * HH + tid] = hn;
        }
        hl[tid] = hn;
    }
    __syncthreads();

    // 3+4. logits / argmax / out / qb: quad 0 only (block-uniform branch)
    if (quad == 0) {
        const float4* hr = (const float4*)hl + lane * 2;
        float4 h0 = hr[0], h1 = hr[1];
        for (int v = w; v < VV; v += 8) {
            const float4* wr = (const float4*)(Wout + (size_t)v * HH) + lane * 2;
            float4 w0 = wr[0], w1 = wr[1];
            float d = w0.x * h0.x + w0.y * h0.y + w0.z * h0.z + w0.w * h0.w +
                      w1.x * h1.x + w1.y * h1.y + w1.z * h1.z + w1.w * h1.w;
#pragma unroll
            for (int off = 1; off < 64; off <<= 1) d += __shfl_xor(d, off, 64);
            if (lane == 0) {
                d += bout[v];
                logl[v] = d;
                out[((size_t)cb * TT + t) * VV + v] = d;
            }
        }
        __syncthreads();

        if (w == 0) {  // argmax, numpy first-max tie-break
            float bv = logl[lane];
            int bi = lane;
            for (int v = lane + 64; v < VV; v += 64) {
                float x = logl[v];
                if (x > bv) { bv = x; bi = v; }
            }
#pragma unroll
            for (int off = 1; off < 64; off <<= 1) {
                float ov = __shfl_xor(bv, off, 64);
                int oi = __shfl_xor(bi, off, 64);
                if (ov > bv || (ov == bv && oi < bi)) { bv = ov; bi = oi; }
            }
            if (lane == 0) chout[cb] = bi;
        } else if (w == 1) {  // qb = h.v0 + s0
            float p = 0.f;
#pragma unroll
            for (int j = 0; j < 8; j++) {
                int k = lane + 64 * j;
                p += hl[k] * v0[k];
            }
#pragma unroll
            for (int off = 1; off < 64; off <<= 1) p += __shfl_xor(p, off, 64);
            if (lane == 0) qb[cb] = p + s0[0];
        }
    }

    // 5. qp quarter: c = quad*128 + (tid&127), k split 4 ways (kq = tid>>7)
    {
        int cl = tid & 127, kq = tid >> 7;
        int c = quad * 128 + cl;
        const float* Pp = P + (size_t)(kq * 128) * CC + c;
        float a = 0.f;
#pragma unroll 8
        for (int kk = 0; kk < 128; kk++)
            a += hl[kq * 128 + kk] * Pp[(size_t)kk * CC];
        red[kq * 128 + cl] = a;
    }
    __syncthreads();
    if (tid < 128) {
        int c = quad * 128 + tid;
        float r = red[tid] + red[128 + tid] + red[256 + tid] + red[384 + tid] + p0[c];
        qp[(size_t)cb * CC + c] = r;
    }
}

// ---------------------------------------------------------------------------

extern "C" void kernel_launch(void* const* d_in, const int* in_sizes, int n_in,
                              void* d_out, int out_size, void* d_ws, size_t ws_size,
                              hipStream_t stream) {
    const float* X    = (const float*)d_in[0];   // [64,1024,512]
    const int*   lab  = (const int*)d_in[1];     // [64,128]
    const float* Icw  = (const float*)d_in[2];   // [512,512]
    const float* Icb  = (const float*)d_in[3];   // [512]
    const float* Hcw  = (const float*)d_in[4];   // [512,512]
    const float* Hcb  = (const float*)d_in[5];   // [512]
    const float* Wih  = (const float*)d_in[6];   // [2048,652]
    const float* bih  = (const float*)d_in[7];   // [2048]
    const float* Whh  = (const float*)d_in[8];   // [2048,512]
    const float* bhh  = (const float*)d_in[9];   // [2048]
    const float* Wout = (const float*)d_in[10];  // [140,512]
    const float* bout = (const float*)d_in[11];  // [140]
    float* out = (float*)d_out;                  // [64,128,140]

    // workspace layout (floats)
    float* ws = (float*)d_ws;
    size_t off = 0;
    float* P        = ws + off; off += 512 * 512;
    float* GT       = ws + off; off += 512 * 2048;
    float* WhhT     = ws + off; off += 512 * 2048;
    float* Wih0T    = ws + off; off += 140 * 2048;
    float* gateb    = ws + off; off += 2048;
    float* p0       = ws + off; off += 512;
    float* v0       = ws + off; off += 512;
    float* s0       = ws + off; off += 64;
    float* h        = ws + off; off += 64 * 512;
    float* cstA     = ws + off; off += 64 * 512;
    float* cstB     = ws + off; off += 64 * 512;
    float* qp       = ws + off; off += 64 * 512;
    float* qb       = ws + off; off += 64;
    float* part_m   = ws + off; off += 64 * NCH;
    float* part_l   = ws + off; off += 64 * NCH;
    float* part_acc = ws + off; off += 64 * NCH * 512;
    float* pg       = ws + off; off += 8 * 64 * 2048;  // aliased as Gtmp in precompute
    int*   charrA   = (int*)(ws + off); off += 64;
    int*   charrB   = (int*)(ws + off); off += 64;
    if (ws_size < off * sizeof(float)) return;  // workspace too small -> fail loudly

    float* Gtmp = pg;  // reuse: Gtmp only live before first step

    // ---- one-time precompute ----
    k_small<<<1, 512, 0, stream>>>(Hcw, Hcb, Icw, Icb, p0, v0, s0);
    k_P<<<dim3(2, 512), 256, 0, stream>>>(Hcw, Icw, P);
    k_G<<<dim3(2, 256), 256, 0, stream>>>(Wih, Icw, Gtmp);
    k_transpose<<<dim3(16, 64), dim3(32, 8), 0, stream>>>(Gtmp, GT, 2048, 512, 512, 0);
    k_transpose<<<dim3(16, 64), dim3(32, 8), 0, stream>>>(Whh, WhhT, 2048, 512, 512, 0);
    k_transpose<<<dim3(5, 64), dim3(32, 8), 0, stream>>>(Wih, Wih0T, 2048, 140, 652, 0);
    k_gate_bias<<<8, 256, 0, stream>>>(Wih, Icb, bih, bhh, gateb);
    k_init<<<64, 512, 0, stream>>>(lab, p0, s0, h, cstA, qp, qb, charrA);

    // ---- sequential decode: 3 kernels/step, cst+charr ping-pong ----
    for (int t = 0; t < TT; t++) {
        const float* cin = (t & 1) ? cstB : cstA;
        float* cout      = (t & 1) ? cstA : cstB;
        const int* chin  = (t & 1) ? charrB : charrA;
        int* chout       = (t & 1) ? charrA : charrB;
        k_flash<<<dim3(NCH, 64), 512, 0, stream>>>(X, qp, qb, part_m, part_l, part_acc, t);
        k_gates<<<dim3(8, 8, 4), 512, 0, stream>>>(part_m, part_l, part_acc, h, GT, WhhT, pg);
        k_updqp<<<256, 512, 0, stream>>>(pg, gateb, Wih0T, Wout, bout, v0, s0, P, p0,
                                         cin, cout, chin, chout, h, qp, qb, out, t);
    }
}